// Round 1
// baseline (1165.477 us; speedup 1.0000x reference)
//
#include <hip/hip_runtime.h>

#define DD 50176          // h*w
#define NB 16             // batches
#define NK 64             // k masks
#define NSPLIT 49         // K-splits per batch
#define NTILE 16          // 64-wide k-tiles per split  (49*16*64 = 50176)
#define TK 64

// workspace layout (float elements)
#define PAB_OFF  0
#define PAB_SIZE ((size_t)NB * NSPLIT * 4096)
#define PA2_OFF  PAB_SIZE
#define PA2_SIZE ((size_t)NB * NSPLIT * 64)
#define PB2_OFF  (PA2_OFF + PA2_SIZE)

// ---------------------------------------------------------------------------
// Kernel 1: split-K partial GEMM  ab[b,i,j] partials + row norms (fp32, deterministic)
// LDS layout: transposed [kk][row] with granule skew col = (row + 4*(kk>>2)) & 63
// -> ds_write (transpose stage) and ds_read_b128 (fragments) both <=2-way conflicts.
// ---------------------------------------------------------------------------
__global__ __launch_bounds__(256) void gemm_partial(const float* __restrict__ A,
                                                    const float* __restrict__ B,
                                                    float* __restrict__ ws) {
  const int s = blockIdx.x;     // split
  const int b = blockIdx.y;     // batch
  const float* Ab = A + (size_t)b * NK * DD;
  const float* Bb = B + (size_t)b * NK * DD;
  __shared__ float As[TK * 64];
  __shared__ float Bs[TK * 64];
  const int tid = threadIdx.x;
  const int ti = tid & 15;      // output row-quad
  const int tj = tid >> 4;      // output col-quad
  const int kq = tid & 15;      // staging: k-quad
  const int r0 = tid >> 4;      // staging: row base

  float c[4][4] = {{0.f, 0.f, 0.f, 0.f}, {0.f, 0.f, 0.f, 0.f},
                   {0.f, 0.f, 0.f, 0.f}, {0.f, 0.f, 0.f, 0.f}};
  float a2[4] = {0.f, 0.f, 0.f, 0.f};
  float b2[4] = {0.f, 0.f, 0.f, 0.f};

  for (int t = 0; t < NTILE; ++t) {
    const int k0 = (s * NTILE + t) * TK;
    __syncthreads();
#pragma unroll
    for (int f = 0; f < 4; ++f) {
      const int r = f * 16 + r0;
      const float4 av = *reinterpret_cast<const float4*>(Ab + (size_t)r * DD + k0 + kq * 4);
      const float4 bv = *reinterpret_cast<const float4*>(Bb + (size_t)r * DD + k0 + kq * 4);
      const int col = (r + 4 * kq) & 63;
      As[(kq * 4 + 0) * 64 + col] = av.x;
      As[(kq * 4 + 1) * 64 + col] = av.y;
      As[(kq * 4 + 2) * 64 + col] = av.z;
      As[(kq * 4 + 3) * 64 + col] = av.w;
      Bs[(kq * 4 + 0) * 64 + col] = bv.x;
      Bs[(kq * 4 + 1) * 64 + col] = bv.y;
      Bs[(kq * 4 + 2) * 64 + col] = bv.z;
      Bs[(kq * 4 + 3) * 64 + col] = bv.w;
    }
    __syncthreads();
#pragma unroll 8
    for (int kk = 0; kk < TK; ++kk) {
      const int g = 4 * (kk >> 2);
      const float4 a4 = *reinterpret_cast<const float4*>(&As[kk * 64 + ((4 * ti + g) & 63)]);
      const float4 b4 = *reinterpret_cast<const float4*>(&Bs[kk * 64 + ((4 * tj + g) & 63)]);
      const float ar[4] = {a4.x, a4.y, a4.z, a4.w};
      const float br[4] = {b4.x, b4.y, b4.z, b4.w};
#pragma unroll
      for (int r = 0; r < 4; ++r)
#pragma unroll
        for (int cc = 0; cc < 4; ++cc)
          c[r][cc] = fmaf(ar[r], br[cc], c[r][cc]);
      if (tj == 0) {
#pragma unroll
        for (int r = 0; r < 4; ++r) a2[r] = fmaf(ar[r], ar[r], a2[r]);
      }
      if (ti == 0) {
#pragma unroll
        for (int cc = 0; cc < 4; ++cc) b2[cc] = fmaf(br[cc], br[cc], b2[cc]);
      }
    }
  }

  float* Pab = ws + PAB_OFF + (size_t)(b * NSPLIT + s) * 4096;
#pragma unroll
  for (int r = 0; r < 4; ++r) {
    const float4 v = make_float4(c[r][0], c[r][1], c[r][2], c[r][3]);
    *reinterpret_cast<float4*>(Pab + (ti * 4 + r) * 64 + tj * 4) = v;
  }
  if (tj == 0) {
    float* Pa2 = ws + PA2_OFF + (size_t)(b * NSPLIT + s) * 64;
#pragma unroll
    for (int r = 0; r < 4; ++r) Pa2[ti * 4 + r] = a2[r];
  }
  if (ti == 0) {
    float* Pb2 = ws + PB2_OFF + (size_t)(b * NSPLIT + s) * 64;
#pragma unroll
    for (int cc = 0; cc < 4; ++cc) Pb2[tj * 4 + cc] = b2[cc];
  }
}

// ---------------------------------------------------------------------------
// Kernel 2: per batch — reduce partials in double, build cost, exact JV LSA
// (wave 0, columns <-> lanes, matches jnp reference incl. argmin tie-break).
// ---------------------------------------------------------------------------
__global__ __launch_bounds__(256) void reduce_lsa(const float* __restrict__ ws,
                                                  int* __restrict__ out) {
  const int b = blockIdx.x;
  __shared__ double costd[64 * 64];
  __shared__ double a2s[64];
  __shared__ double b2s[64];
  __shared__ double u_sh[65];
  __shared__ int p_sh[65];
  const int tid = threadIdx.x;

  // reduce norms (deterministic fixed-order sums)
  if (tid < 64) {
    double sum = 0.0;
    for (int sp = 0; sp < NSPLIT; ++sp)
      sum += (double)ws[PA2_OFF + (size_t)(b * NSPLIT + sp) * 64 + tid];
    a2s[tid] = sum;
  }
  if (tid >= 64 && tid < 128) {
    const int l = tid - 64;
    double sum = 0.0;
    for (int sp = 0; sp < NSPLIT; ++sp)
      sum += (double)ws[PB2_OFF + (size_t)(b * NSPLIT + sp) * 64 + l];
    b2s[l] = sum;
  }

  // reduce ab partials: thread -> (row i, 16 cols)
  const int i = tid >> 2;
  const int jq = tid & 3;
  double acc[16];
#pragma unroll
  for (int f = 0; f < 16; ++f) acc[f] = 0.0;
  for (int sp = 0; sp < NSPLIT; ++sp) {
    const float* base = ws + PAB_OFF + (size_t)(b * NSPLIT + sp) * 4096 + i * 64 + jq * 16;
#pragma unroll
    for (int f = 0; f < 4; ++f) {
      const float4 v = *reinterpret_cast<const float4*>(base + 4 * f);
      acc[4 * f + 0] += (double)v.x;
      acc[4 * f + 1] += (double)v.y;
      acc[4 * f + 2] += (double)v.z;
      acc[4 * f + 3] += (double)v.w;
    }
  }
  __syncthreads();
#pragma unroll
  for (int f = 0; f < 16; ++f) {
    const int j = jq * 16 + f;
    const double c2 = a2s[i] + b2s[j] - 2.0 * acc[f];
    costd[i * 64 + j] = sqrt(c2 > 0.0 ? c2 : 0.0);
  }
  __syncthreads();

  if (tid < 64) {
    const int l = tid;                 // lane l owns column j = l+1
    volatile double* uu = u_sh;
    volatile int* pp = p_sh;
    const double INFD = 1e30;
    double v_l = 0.0;
    uu[l] = 0.0;
    pp[l] = 0;
    if (l == 0) { uu[64] = 0.0; pp[64] = 0; }

    for (int i_row = 1; i_row <= 64; ++i_row) {
      double minv_l = INFD;
      int way_l = 0;
      bool used_l = false;
      if (l == 0) pp[0] = i_row;
      int j0 = 0;
      while (true) {
        const int i0 = pp[j0];         // uniform broadcast read
        if (i0 == 0) break;
        if (j0 > 0 && l == j0 - 1) used_l = true;
        const double ui0 = uu[i0];
        const double cur = costd[(i0 - 1) * 64 + l] - ui0 - v_l;
        if (!used_l && cur < minv_l) { minv_l = cur; way_l = j0; }
        double candv = used_l ? INFD : minv_l;
        int candi = l;
#pragma unroll
        for (int off = 1; off < 64; off <<= 1) {
          const double ov = __shfl_xor(candv, off, 64);
          const int oi = __shfl_xor(candi, off, 64);
          if (ov < candv || (ov == candv && oi < candi)) { candv = ov; candi = oi; }
        }
        const double delta = candv;    // uniform
        if (used_l) {
          const int pj = pp[l + 1];    // matched row of this used column (distinct per lane)
          uu[pj] = uu[pj] + delta;
          v_l -= delta;
        } else {
          minv_l -= delta;
        }
        if (l == 0) uu[i_row] = uu[i_row] + delta;  // j=0 slot (used[0]) -> u[i] += delta
        j0 = candi + 1;
      }
      // augment along alternating path
      while (j0 != 0) {
        const int j1 = __shfl(way_l, j0 - 1, 64);
        const int pj1 = pp[j1];
        if (l == 0) pp[j0] = pj1;
        j0 = j1;
      }
    }
    const int row = pp[l + 1];         // 1..64: row matched to column l+1
    out[b * NK + l] = l;                         // inds  (arange)
    out[NB * NK + b * NK + (row - 1)] = l;       // inds2 (col of row)
  }
}

extern "C" void kernel_launch(void* const* d_in, const int* in_sizes, int n_in,
                              void* d_out, int out_size, void* d_ws, size_t ws_size,
                              hipStream_t stream) {
  const float* A = (const float*)d_in[0];   // outputs [16,64,50176] fp32
  const float* B = (const float*)d_in[1];   // targets [16,64,50176] fp32
  float* ws = (float*)d_ws;                 // needs ~12.7 MiB
  int* out = (int*)d_out;                   // 2048 int32: [inds | inds2]

  dim3 g1(NSPLIT, NB);
  gemm_partial<<<g1, 256, 0, stream>>>(A, B, ws);
  reduce_lsa<<<NB, 256, 0, stream>>>(ws, out);
}

// Round 2
// 715.405 us; speedup vs baseline: 1.6291x; 1.6291x over previous
//
#include <hip/hip_runtime.h>

#define DD 50176          // h*w
#define NB 16             // batches
#define NK 64             // k masks
#define NSPLIT 49         // K-splits per batch
#define NTILE 16          // 64-wide k-tiles per split  (49*16*64 = 50176)
#define TK 64

// workspace layout (float elements)
#define PAB_OFF  0
#define PAB_SIZE ((size_t)NB * NSPLIT * 4096)
#define PA2_OFF  PAB_SIZE
#define PA2_SIZE ((size_t)NB * NSPLIT * 64)
#define PB2_OFF  (PA2_OFF + PA2_SIZE)

// ---------------------------------------------------------------------------
// Kernel 1: split-K partial GEMM  ab[b,i,j] partials + row norms (fp32, deterministic)
// LDS layout: transposed [kk][row] with granule skew col = (row + 4*(kk>>2)) & 63
// -> ds_write (transpose stage) and ds_read_b128 (fragments) both <=2-way conflicts.
// ---------------------------------------------------------------------------
__global__ __launch_bounds__(256) void gemm_partial(const float* __restrict__ A,
                                                    const float* __restrict__ B,
                                                    float* __restrict__ ws) {
  const int s = blockIdx.x;     // split
  const int b = blockIdx.y;     // batch
  const float* Ab = A + (size_t)b * NK * DD;
  const float* Bb = B + (size_t)b * NK * DD;
  __shared__ float As[TK * 64];
  __shared__ float Bs[TK * 64];
  const int tid = threadIdx.x;
  const int ti = tid & 15;      // output row-quad
  const int tj = tid >> 4;      // output col-quad
  const int kq = tid & 15;      // staging: k-quad
  const int r0 = tid >> 4;      // staging: row base

  float c[4][4] = {{0.f, 0.f, 0.f, 0.f}, {0.f, 0.f, 0.f, 0.f},
                   {0.f, 0.f, 0.f, 0.f}, {0.f, 0.f, 0.f, 0.f}};
  float a2[4] = {0.f, 0.f, 0.f, 0.f};
  float b2[4] = {0.f, 0.f, 0.f, 0.f};

  for (int t = 0; t < NTILE; ++t) {
    const int k0 = (s * NTILE + t) * TK;
    __syncthreads();
#pragma unroll
    for (int f = 0; f < 4; ++f) {
      const int r = f * 16 + r0;
      const float4 av = *reinterpret_cast<const float4*>(Ab + (size_t)r * DD + k0 + kq * 4);
      const float4 bv = *reinterpret_cast<const float4*>(Bb + (size_t)r * DD + k0 + kq * 4);
      const int col = (r + 4 * kq) & 63;
      As[(kq * 4 + 0) * 64 + col] = av.x;
      As[(kq * 4 + 1) * 64 + col] = av.y;
      As[(kq * 4 + 2) * 64 + col] = av.z;
      As[(kq * 4 + 3) * 64 + col] = av.w;
      Bs[(kq * 4 + 0) * 64 + col] = bv.x;
      Bs[(kq * 4 + 1) * 64 + col] = bv.y;
      Bs[(kq * 4 + 2) * 64 + col] = bv.z;
      Bs[(kq * 4 + 3) * 64 + col] = bv.w;
    }
    __syncthreads();
#pragma unroll 8
    for (int kk = 0; kk < TK; ++kk) {
      const int g = 4 * (kk >> 2);
      const float4 a4 = *reinterpret_cast<const float4*>(&As[kk * 64 + ((4 * ti + g) & 63)]);
      const float4 b4 = *reinterpret_cast<const float4*>(&Bs[kk * 64 + ((4 * tj + g) & 63)]);
      const float ar[4] = {a4.x, a4.y, a4.z, a4.w};
      const float br[4] = {b4.x, b4.y, b4.z, b4.w};
#pragma unroll
      for (int r = 0; r < 4; ++r)
#pragma unroll
        for (int cc = 0; cc < 4; ++cc)
          c[r][cc] = fmaf(ar[r], br[cc], c[r][cc]);
      if (tj == 0) {
#pragma unroll
        for (int r = 0; r < 4; ++r) a2[r] = fmaf(ar[r], ar[r], a2[r]);
      }
      if (ti == 0) {
#pragma unroll
        for (int cc = 0; cc < 4; ++cc) b2[cc] = fmaf(br[cc], br[cc], b2[cc]);
      }
    }
  }

  float* Pab = ws + PAB_OFF + (size_t)(b * NSPLIT + s) * 4096;
#pragma unroll
  for (int r = 0; r < 4; ++r) {
    const float4 v = make_float4(c[r][0], c[r][1], c[r][2], c[r][3]);
    *reinterpret_cast<float4*>(Pab + (ti * 4 + r) * 64 + tj * 4) = v;
  }
  if (tj == 0) {
    float* Pa2 = ws + PA2_OFF + (size_t)(b * NSPLIT + s) * 64;
#pragma unroll
    for (int r = 0; r < 4; ++r) Pa2[ti * 4 + r] = a2[r];
  }
  if (ti == 0) {
    float* Pb2 = ws + PB2_OFF + (size_t)(b * NSPLIT + s) * 64;
#pragma unroll
    for (int cc = 0; cc < 4; ++cc) Pb2[tj * 4 + cc] = b2[cc];
  }
}

// ---------------------------------------------------------------------------
// Kernel 2: per batch — reduce partials in double, build cost, exact JV LSA.
// Solver state lives in registers, one entry per lane (lane l <-> column l+1,
// and lane l <-> row l+1 for u/colof). Uniform-index cross-lane reads use
// v_readlane (VALU latency) instead of volatile-LDS round trips. Min-reduce is
// value-only butterfly; argmin via ballot+ffs (first-index tie-break == jnp).
// Numerically identical op sequence to the previous (passing) version.
// ---------------------------------------------------------------------------
__device__ __forceinline__ double readlane_d(double x, int lane) {
  const int lo = __builtin_amdgcn_readlane(__double2loint(x), lane);
  const int hi = __builtin_amdgcn_readlane(__double2hiint(x), lane);
  return __hiloint2double(hi, lo);
}

__global__ __launch_bounds__(256) void reduce_lsa(const float* __restrict__ ws,
                                                  int* __restrict__ out) {
  const int b = blockIdx.x;
  __shared__ double costd[64 * 64];
  __shared__ double a2s[64];
  __shared__ double b2s[64];
  const int tid = threadIdx.x;

  // reduce norms (deterministic fixed-order sums)
  if (tid < 64) {
    double sum = 0.0;
    for (int sp = 0; sp < NSPLIT; ++sp)
      sum += (double)ws[PA2_OFF + (size_t)(b * NSPLIT + sp) * 64 + tid];
    a2s[tid] = sum;
  }
  if (tid >= 64 && tid < 128) {
    const int l = tid - 64;
    double sum = 0.0;
    for (int sp = 0; sp < NSPLIT; ++sp)
      sum += (double)ws[PB2_OFF + (size_t)(b * NSPLIT + sp) * 64 + l];
    b2s[l] = sum;
  }

  // reduce ab partials: thread -> (row i, 16 cols)
  const int i = tid >> 2;
  const int jq = tid & 3;
  double acc[16];
#pragma unroll
  for (int f = 0; f < 16; ++f) acc[f] = 0.0;
  for (int sp = 0; sp < NSPLIT; ++sp) {
    const float* base = ws + PAB_OFF + (size_t)(b * NSPLIT + sp) * 4096 + i * 64 + jq * 16;
#pragma unroll
    for (int f = 0; f < 4; ++f) {
      const float4 v = *reinterpret_cast<const float4*>(base + 4 * f);
      acc[4 * f + 0] += (double)v.x;
      acc[4 * f + 1] += (double)v.y;
      acc[4 * f + 2] += (double)v.z;
      acc[4 * f + 3] += (double)v.w;
    }
  }
  __syncthreads();
#pragma unroll
  for (int f = 0; f < 16; ++f) {
    const int j = jq * 16 + f;
    const double c2 = a2s[i] + b2s[j] - 2.0 * acc[f];
    costd[i * 64 + j] = sqrt(c2 > 0.0 ? c2 : 0.0);
  }
  __syncthreads();

  if (tid < 64) {
    const int l = tid;                 // lane l owns column j = l+1 (and row l+1 for u/colof)
    const double INFD = 1e30;
    double v_l = 0.0;                  // v[l+1]
    double u_l = 0.0;                  // u[l+1]
    int p_l = 0;                       // p[l+1]  (row matched to column l+1)
    int colof_l = 0;                   // column matched to row l+1 (0 = unmatched)

    for (int i_row = 1; i_row <= 64; ++i_row) {
      double minv = INFD;
      int way_l = 0;
      bool used = false;
      int j0 = 0;

      while (true) {
        const int i0 = (j0 == 0) ? i_row : __builtin_amdgcn_readlane(p_l, j0 - 1);
        if (i0 == 0) break;            // column j0 is free -> augment
        if (j0 > 0 && l == j0 - 1) used = true;
        const double ui0 = readlane_d(u_l, i0 - 1);
        const double cur = costd[(i0 - 1) * 64 + l] - ui0 - v_l;
        if (!used && cur < minv) { minv = cur; way_l = j0; }
        const double cand = used ? INFD : minv;
        double m = cand;
#pragma unroll
        for (int off = 1; off < 64; off <<= 1) {
          const double o = __shfl_xor(m, off, 64);
          m = (o < m) ? o : m;
        }
        const unsigned long long eqm = __ballot(cand == m);
        const int jmin = __ffsll(eqm) - 1;      // first-index tie-break == argmin
        const double delta = m;
        if (used) v_l -= delta; else minv -= delta;
        const unsigned long long um = __ballot(used);
        // u[p[j]] += delta for used j (incl. j=0: p[0]=i_row). Row r=l+1 is hit iff
        // r == i_row, or r is matched to a used column (colof_l bit set in um).
        const bool addu = (l + 1 == i_row) ||
                          (colof_l != 0 && ((um >> (colof_l - 1)) & 1ULL));
        if (addu) u_l += delta;
        j0 = __builtin_amdgcn_readfirstlane(jmin + 1);
      }

      // augment along alternating path (j0 points at a free column)
      while (j0 != 0) {
        const int j1 = __builtin_amdgcn_readlane(way_l, j0 - 1);
        const int pj1 = (j1 == 0) ? i_row : __builtin_amdgcn_readlane(p_l, j1 - 1);
        if (l == j0 - 1) p_l = pj1;    // p[j0] = p[j1]
        if (l == pj1 - 1) colof_l = j0;// row pj1 now matched to column j0
        j0 = j1;
      }
    }

    out[b * NK + l] = l;                       // inds  (arange)
    out[NB * NK + b * NK + l] = colof_l - 1;   // inds2 (col of row l+1), coalesced
  }
}

extern "C" void kernel_launch(void* const* d_in, const int* in_sizes, int n_in,
                              void* d_out, int out_size, void* d_ws, size_t ws_size,
                              hipStream_t stream) {
  const float* A = (const float*)d_in[0];   // outputs [16,64,50176] fp32
  const float* B = (const float*)d_in[1];   // targets [16,64,50176] fp32
  float* ws = (float*)d_ws;                 // needs ~12.7 MiB
  int* out = (int*)d_out;                   // 2048 int32: [inds | inds2]

  dim3 g1(NSPLIT, NB);
  gemm_partial<<<g1, 256, 0, stream>>>(A, B, ws);
  reduce_lsa<<<NB, 256, 0, stream>>>(ws, out);
}

// Round 3
// 571.511 us; speedup vs baseline: 2.0393x; 1.2518x over previous
//
#include <hip/hip_runtime.h>

#define DD 50176          // h*w
#define NB 16             // batches
#define NK 64             // k masks
#define NSPLIT 49         // K-splits per batch
#define NTILE 16          // 64-wide k-tiles per split  (49*16*64 = 50176)
#define TK 64

// workspace layout (float elements)
#define PAB_OFF  0
#define PAB_SIZE ((size_t)NB * NSPLIT * 4096)
#define PA2_OFF  PAB_SIZE
#define PA2_SIZE ((size_t)NB * NSPLIT * 64)
#define PB2_OFF  (PA2_OFF + PA2_SIZE)

// ---------------------------------------------------------------------------
// Kernel 1: split-K partial GEMM  ab[b,i,j] partials + row norms (fp32, deterministic)
// ---------------------------------------------------------------------------
__global__ __launch_bounds__(256) void gemm_partial(const float* __restrict__ A,
                                                    const float* __restrict__ B,
                                                    float* __restrict__ ws) {
  const int s = blockIdx.x;     // split
  const int b = blockIdx.y;     // batch
  const float* Ab = A + (size_t)b * NK * DD;
  const float* Bb = B + (size_t)b * NK * DD;
  __shared__ float As[TK * 64];
  __shared__ float Bs[TK * 64];
  const int tid = threadIdx.x;
  const int ti = tid & 15;      // output row-quad
  const int tj = tid >> 4;      // output col-quad
  const int kq = tid & 15;      // staging: k-quad
  const int r0 = tid >> 4;      // staging: row base

  float c[4][4] = {{0.f, 0.f, 0.f, 0.f}, {0.f, 0.f, 0.f, 0.f},
                   {0.f, 0.f, 0.f, 0.f}, {0.f, 0.f, 0.f, 0.f}};
  float a2[4] = {0.f, 0.f, 0.f, 0.f};
  float b2[4] = {0.f, 0.f, 0.f, 0.f};

  for (int t = 0; t < NTILE; ++t) {
    const int k0 = (s * NTILE + t) * TK;
    __syncthreads();
#pragma unroll
    for (int f = 0; f < 4; ++f) {
      const int r = f * 16 + r0;
      const float4 av = *reinterpret_cast<const float4*>(Ab + (size_t)r * DD + k0 + kq * 4);
      const float4 bv = *reinterpret_cast<const float4*>(Bb + (size_t)r * DD + k0 + kq * 4);
      const int col = (r + 4 * kq) & 63;
      As[(kq * 4 + 0) * 64 + col] = av.x;
      As[(kq * 4 + 1) * 64 + col] = av.y;
      As[(kq * 4 + 2) * 64 + col] = av.z;
      As[(kq * 4 + 3) * 64 + col] = av.w;
      Bs[(kq * 4 + 0) * 64 + col] = bv.x;
      Bs[(kq * 4 + 1) * 64 + col] = bv.y;
      Bs[(kq * 4 + 2) * 64 + col] = bv.z;
      Bs[(kq * 4 + 3) * 64 + col] = bv.w;
    }
    __syncthreads();
#pragma unroll 8
    for (int kk = 0; kk < TK; ++kk) {
      const int g = 4 * (kk >> 2);
      const float4 a4 = *reinterpret_cast<const float4*>(&As[kk * 64 + ((4 * ti + g) & 63)]);
      const float4 b4 = *reinterpret_cast<const float4*>(&Bs[kk * 64 + ((4 * tj + g) & 63)]);
      const float ar[4] = {a4.x, a4.y, a4.z, a4.w};
      const float br[4] = {b4.x, b4.y, b4.z, b4.w};
#pragma unroll
      for (int r = 0; r < 4; ++r)
#pragma unroll
        for (int cc = 0; cc < 4; ++cc)
          c[r][cc] = fmaf(ar[r], br[cc], c[r][cc]);
      if (tj == 0) {
#pragma unroll
        for (int r = 0; r < 4; ++r) a2[r] = fmaf(ar[r], ar[r], a2[r]);
      }
      if (ti == 0) {
#pragma unroll
        for (int cc = 0; cc < 4; ++cc) b2[cc] = fmaf(br[cc], br[cc], b2[cc]);
      }
    }
  }

  float* Pab = ws + PAB_OFF + (size_t)(b * NSPLIT + s) * 4096;
#pragma unroll
  for (int r = 0; r < 4; ++r) {
    const float4 v = make_float4(c[r][0], c[r][1], c[r][2], c[r][3]);
    *reinterpret_cast<float4*>(Pab + (ti * 4 + r) * 64 + tj * 4) = v;
  }
  if (tj == 0) {
    float* Pa2 = ws + PA2_OFF + (size_t)(b * NSPLIT + s) * 64;
#pragma unroll
    for (int r = 0; r < 4; ++r) Pa2[ti * 4 + r] = a2[r];
  }
  if (ti == 0) {
    float* Pb2 = ws + PB2_OFF + (size_t)(b * NSPLIT + s) * 64;
#pragma unroll
    for (int cc = 0; cc < 4; ++cc) Pb2[tj * 4 + cc] = b2[cc];
  }
}

// ---------------------------------------------------------------------------
// Kernel 2: per batch — reduce partials in double, build cost, exact JV LSA.
// Min-reduce now via VALU-only DPP on a monotone u64 key (row_shr 1/2/4/8 +
// row_bcast 15/31 -> lane 63), replacing the ds_swizzle double butterfly.
// Exact same min value (bijective key) and same first-index tie-break.
// ---------------------------------------------------------------------------
__device__ __forceinline__ double readlane_d(double x, int lane) {
  const int lo = __builtin_amdgcn_readlane(__double2loint(x), lane);
  const int hi = __builtin_amdgcn_readlane(__double2hiint(x), lane);
  return __hiloint2double(hi, lo);
}

template <int CTRL, int RMASK>
__device__ __forceinline__ unsigned long long dpp_min_step(unsigned long long k) {
  const unsigned ohi = (unsigned)__builtin_amdgcn_update_dpp(
      -1, (int)(unsigned)(k >> 32), CTRL, RMASK, 0xf, false);
  const unsigned olo = (unsigned)__builtin_amdgcn_update_dpp(
      -1, (int)(unsigned)k, CTRL, RMASK, 0xf, false);
  const unsigned long long o = ((unsigned long long)ohi << 32) | olo;
  return o < k ? o : k;
}

__global__ __launch_bounds__(256) void reduce_lsa(const float* __restrict__ ws,
                                                  int* __restrict__ out) {
  const int b = blockIdx.x;
  __shared__ double costd[64 * 64];
  __shared__ double a2s[64];
  __shared__ double b2s[64];
  const int tid = threadIdx.x;

  // reduce norms (deterministic fixed-order sums)
  if (tid < 64) {
    double sum = 0.0;
    for (int sp = 0; sp < NSPLIT; ++sp)
      sum += (double)ws[PA2_OFF + (size_t)(b * NSPLIT + sp) * 64 + tid];
    a2s[tid] = sum;
  }
  if (tid >= 64 && tid < 128) {
    const int l = tid - 64;
    double sum = 0.0;
    for (int sp = 0; sp < NSPLIT; ++sp)
      sum += (double)ws[PB2_OFF + (size_t)(b * NSPLIT + sp) * 64 + l];
    b2s[l] = sum;
  }

  // reduce ab partials: thread -> (row i, 16 cols)
  const int i = tid >> 2;
  const int jq = tid & 3;
  double acc[16];
#pragma unroll
  for (int f = 0; f < 16; ++f) acc[f] = 0.0;
  for (int sp = 0; sp < NSPLIT; ++sp) {
    const float* base = ws + PAB_OFF + (size_t)(b * NSPLIT + sp) * 4096 + i * 64 + jq * 16;
#pragma unroll
    for (int f = 0; f < 4; ++f) {
      const float4 v = *reinterpret_cast<const float4*>(base + 4 * f);
      acc[4 * f + 0] += (double)v.x;
      acc[4 * f + 1] += (double)v.y;
      acc[4 * f + 2] += (double)v.z;
      acc[4 * f + 3] += (double)v.w;
    }
  }
  __syncthreads();
#pragma unroll
  for (int f = 0; f < 16; ++f) {
    const int j = jq * 16 + f;
    const double c2 = a2s[i] + b2s[j] - 2.0 * acc[f];
    costd[i * 64 + j] = sqrt(c2 > 0.0 ? c2 : 0.0);
  }
  __syncthreads();

  if (tid < 64) {
    const int l = tid;                 // lane l owns column j = l+1 (and row l+1 for u/colof)
    const double INFD = 1e30;
    const unsigned long long SGN = 0x8000000000000000ULL;
    double v_l = 0.0;                  // v[l+1]
    double u_l = 0.0;                  // u[l+1]
    int p_l = 0;                       // p[l+1]  (row matched to column l+1)
    int colof_l = 0;                   // column matched to row l+1 (0 = unmatched)

    for (int i_row = 1; i_row <= 64; ++i_row) {
      double minv = INFD;
      int way_l = 0;
      bool used = false;
      int j0 = 0;

      while (true) {
        const int i0 = (j0 == 0) ? i_row : __builtin_amdgcn_readlane(p_l, j0 - 1);
        if (i0 == 0) break;            // column j0 is free -> augment
        if (j0 > 0 && l == j0 - 1) used = true;
        const double ui0 = readlane_d(u_l, i0 - 1);
        const double cur = costd[(i0 - 1) * 64 + l] - ui0 - v_l;
        if (!used && cur < minv) { minv = cur; way_l = j0; }
        const double cand = used ? INFD : minv;

        // exact min via monotone-u64 key, VALU-only DPP reduce to lane 63
        const unsigned long long cb = (unsigned long long)__double_as_longlong(cand);
        const unsigned long long key =
            cb ^ ((unsigned long long)((long long)cb >> 63) | SGN);
        unsigned long long r = key;
        r = dpp_min_step<0x111, 0xf>(r);   // row_shr:1
        r = dpp_min_step<0x112, 0xf>(r);   // row_shr:2
        r = dpp_min_step<0x114, 0xf>(r);   // row_shr:4
        r = dpp_min_step<0x118, 0xf>(r);   // row_shr:8
        r = dpp_min_step<0x142, 0xa>(r);   // row_bcast:15 (rows 1,3)
        r = dpp_min_step<0x143, 0xc>(r);   // row_bcast:31 (rows 2,3)
        const unsigned mhi = (unsigned)__builtin_amdgcn_readlane((int)(unsigned)(r >> 32), 63);
        const unsigned mlo = (unsigned)__builtin_amdgcn_readlane((int)(unsigned)r, 63);
        const unsigned long long mkey = ((unsigned long long)mhi << 32) | mlo;
        const unsigned long long mbits = (mkey & SGN) ? (mkey ^ SGN) : ~mkey;
        const double delta = __longlong_as_double((long long)mbits);

        const unsigned long long eqm = __ballot(key == mkey);
        const int jmin = __ffsll(eqm) - 1;      // first-index tie-break == argmin

        if (used) v_l -= delta; else minv -= delta;
        const unsigned long long um = __ballot(used);
        // u[p[j]] += delta for used j (incl. j=0: p[0]=i_row). Row r=l+1 is hit iff
        // r == i_row, or r is matched to a used column (colof_l bit set in um).
        const bool addu = (l + 1 == i_row) ||
                          (colof_l != 0 && ((um >> (colof_l - 1)) & 1ULL));
        if (addu) u_l += delta;
        j0 = jmin + 1;
      }

      // augment along alternating path (j0 points at a free column)
      while (j0 != 0) {
        const int j1 = __builtin_amdgcn_readlane(way_l, j0 - 1);
        const int pj1 = (j1 == 0) ? i_row : __builtin_amdgcn_readlane(p_l, j1 - 1);
        if (l == j0 - 1) p_l = pj1;    // p[j0] = p[j1]
        if (l == pj1 - 1) colof_l = j0;// row pj1 now matched to column j0
        j0 = j1;
      }
    }

    out[b * NK + l] = l;                       // inds  (arange)
    out[NB * NK + b * NK + l] = colof_l - 1;   // inds2 (col of row l+1), coalesced
  }
}

extern "C" void kernel_launch(void* const* d_in, const int* in_sizes, int n_in,
                              void* d_out, int out_size, void* d_ws, size_t ws_size,
                              hipStream_t stream) {
  const float* A = (const float*)d_in[0];   // outputs [16,64,50176] fp32
  const float* B = (const float*)d_in[1];   // targets [16,64,50176] fp32
  float* ws = (float*)d_ws;                 // needs ~12.7 MiB
  int* out = (int*)d_out;                   // 2048 int32: [inds | inds2]

  dim3 g1(NSPLIT, NB);
  gemm_partial<<<g1, 256, 0, stream>>>(A, B, ws);
  reduce_lsa<<<NB, 256, 0, stream>>>(ws, out);
}

// Round 4
// 511.272 us; speedup vs baseline: 2.2796x; 1.1178x over previous
//
#include <hip/hip_runtime.h>

#define DD 50176          // h*w
#define NB 16             // batches
#define NK 64             // k masks
#define NSPLIT 49         // K-splits per batch
#define NTILE 16          // 64-wide k-tiles per split  (49*16*64 = 50176)
#define TK 64

// workspace layout (float elements)
#define PAB_OFF  0
#define PAB_SIZE ((size_t)NB * NSPLIT * 4096)
#define PA2_OFF  PAB_SIZE
#define PA2_SIZE ((size_t)NB * NSPLIT * 64)
#define PB2_OFF  (PA2_OFF + PA2_SIZE)

// ---------------------------------------------------------------------------
// Kernel 1: split-K partial GEMM, 64 threads/block, 8x8 register tile/thread.
// LDS transposed layout [kk][col] with granule skew col = (row + 4*(kk>>2)) & 63;
// staging ds_write and fragment ds_read_b128 are both <=2-way bank conflicts.
// 1 B LDS read / FLOP -> FMA-issue-bound; 784 blocks < 1024 SIMDs (all resident).
// ---------------------------------------------------------------------------
__global__ __launch_bounds__(64) void gemm_partial(const float* __restrict__ A,
                                                   const float* __restrict__ B,
                                                   float* __restrict__ ws) {
  const int s = blockIdx.x;     // split
  const int b = blockIdx.y;     // batch
  const float* Ab = A + (size_t)b * NK * DD;
  const float* Bb = B + (size_t)b * NK * DD;
  __shared__ float As[TK * 64];
  __shared__ float Bs[TK * 64];
  const int tid = threadIdx.x;  // 0..63
  const int ti = tid >> 3;      // output row-octet 0..7
  const int tj = tid & 7;       // output col-octet 0..7
  const int kq = tid & 15;      // staging: k-granule 0..15
  const int r0 = tid >> 4;      // staging: row base 0..3

  float c[8][8];
#pragma unroll
  for (int r = 0; r < 8; ++r)
#pragma unroll
    for (int cc = 0; cc < 8; ++cc) c[r][cc] = 0.f;
  float a2[8] = {0.f, 0.f, 0.f, 0.f, 0.f, 0.f, 0.f, 0.f};
  float b2[8] = {0.f, 0.f, 0.f, 0.f, 0.f, 0.f, 0.f, 0.f};

  for (int t = 0; t < NTILE; ++t) {
    const int k0 = (s * NTILE + t) * TK;
    __syncthreads();
#pragma unroll
    for (int f = 0; f < 16; ++f) {
      const int r = f * 4 + r0;
      const float4 av = *reinterpret_cast<const float4*>(Ab + (size_t)r * DD + k0 + kq * 4);
      const float4 bv = *reinterpret_cast<const float4*>(Bb + (size_t)r * DD + k0 + kq * 4);
      const int col = (r + 4 * kq) & 63;
      As[(kq * 4 + 0) * 64 + col] = av.x;
      As[(kq * 4 + 1) * 64 + col] = av.y;
      As[(kq * 4 + 2) * 64 + col] = av.z;
      As[(kq * 4 + 3) * 64 + col] = av.w;
      Bs[(kq * 4 + 0) * 64 + col] = bv.x;
      Bs[(kq * 4 + 1) * 64 + col] = bv.y;
      Bs[(kq * 4 + 2) * 64 + col] = bv.z;
      Bs[(kq * 4 + 3) * 64 + col] = bv.w;
    }
    __syncthreads();
#pragma unroll 4
    for (int kk = 0; kk < TK; ++kk) {
      const int g = 4 * (kk >> 2);
      const float4 a0 = *reinterpret_cast<const float4*>(&As[kk * 64 + ((8 * ti + g) & 63)]);
      const float4 a1 = *reinterpret_cast<const float4*>(&As[kk * 64 + ((8 * ti + 4 + g) & 63)]);
      const float4 b0 = *reinterpret_cast<const float4*>(&Bs[kk * 64 + ((8 * tj + g) & 63)]);
      const float4 b1 = *reinterpret_cast<const float4*>(&Bs[kk * 64 + ((8 * tj + 4 + g) & 63)]);
      const float ar[8] = {a0.x, a0.y, a0.z, a0.w, a1.x, a1.y, a1.z, a1.w};
      const float br[8] = {b0.x, b0.y, b0.z, b0.w, b1.x, b1.y, b1.z, b1.w};
#pragma unroll
      for (int r = 0; r < 8; ++r)
#pragma unroll
        for (int cc = 0; cc < 8; ++cc)
          c[r][cc] = fmaf(ar[r], br[cc], c[r][cc]);
      if (tj == 0) {
#pragma unroll
        for (int r = 0; r < 8; ++r) a2[r] = fmaf(ar[r], ar[r], a2[r]);
      }
      if (ti == 0) {
#pragma unroll
        for (int cc = 0; cc < 8; ++cc) b2[cc] = fmaf(br[cc], br[cc], b2[cc]);
      }
    }
  }

  float* Pab = ws + PAB_OFF + (size_t)(b * NSPLIT + s) * 4096;
#pragma unroll
  for (int r = 0; r < 8; ++r) {
    *reinterpret_cast<float4*>(Pab + (ti * 8 + r) * 64 + tj * 8) =
        make_float4(c[r][0], c[r][1], c[r][2], c[r][3]);
    *reinterpret_cast<float4*>(Pab + (ti * 8 + r) * 64 + tj * 8 + 4) =
        make_float4(c[r][4], c[r][5], c[r][6], c[r][7]);
  }
  if (tj == 0) {
    float* Pa2 = ws + PA2_OFF + (size_t)(b * NSPLIT + s) * 64;
#pragma unroll
    for (int r = 0; r < 8; ++r) Pa2[ti * 8 + r] = a2[r];
  }
  if (ti == 0) {
    float* Pb2 = ws + PB2_OFF + (size_t)(b * NSPLIT + s) * 64;
#pragma unroll
    for (int cc = 0; cc < 8; ++cc) Pb2[tj * 8 + cc] = b2[cc];
  }
}

// ---------------------------------------------------------------------------
// Kernel 2: per batch — reduce partials in double, build cost, exact JV LSA
// with column-reduction init (v[j]=colmin, greedy tight matching, u=0) and
// register-resident Dijkstra (DPP u64-key min) for the remaining free rows.
// Output = unique optimal assignment (doubles: ties measure-zero).
// ---------------------------------------------------------------------------
__device__ __forceinline__ double readlane_d(double x, int lane) {
  const int lo = __builtin_amdgcn_readlane(__double2loint(x), lane);
  const int hi = __builtin_amdgcn_readlane(__double2hiint(x), lane);
  return __hiloint2double(hi, lo);
}

template <int CTRL, int RMASK>
__device__ __forceinline__ unsigned long long dpp_min_step(unsigned long long k) {
  const unsigned ohi = (unsigned)__builtin_amdgcn_update_dpp(
      -1, (int)(unsigned)(k >> 32), CTRL, RMASK, 0xf, false);
  const unsigned olo = (unsigned)__builtin_amdgcn_update_dpp(
      -1, (int)(unsigned)k, CTRL, RMASK, 0xf, false);
  const unsigned long long o = ((unsigned long long)ohi << 32) | olo;
  return o < k ? o : k;
}

__global__ __launch_bounds__(256) void reduce_lsa(const float* __restrict__ ws,
                                                  int* __restrict__ out) {
  const int b = blockIdx.x;
  __shared__ double costd[64 * 64];
  __shared__ double a2s[64];
  __shared__ double b2s[64];
  const int tid = threadIdx.x;

  // reduce norms (deterministic fixed-order sums)
  if (tid < 64) {
    double sum = 0.0;
    for (int sp = 0; sp < NSPLIT; ++sp)
      sum += (double)ws[PA2_OFF + (size_t)(b * NSPLIT + sp) * 64 + tid];
    a2s[tid] = sum;
  }
  if (tid >= 64 && tid < 128) {
    const int l = tid - 64;
    double sum = 0.0;
    for (int sp = 0; sp < NSPLIT; ++sp)
      sum += (double)ws[PB2_OFF + (size_t)(b * NSPLIT + sp) * 64 + l];
    b2s[l] = sum;
  }

  // reduce ab partials: thread -> (row i, 16 cols)
  const int i = tid >> 2;
  const int jq = tid & 3;
  double acc[16];
#pragma unroll
  for (int f = 0; f < 16; ++f) acc[f] = 0.0;
  for (int sp = 0; sp < NSPLIT; ++sp) {
    const float* base = ws + PAB_OFF + (size_t)(b * NSPLIT + sp) * 4096 + i * 64 + jq * 16;
#pragma unroll
    for (int f = 0; f < 4; ++f) {
      const float4 v = *reinterpret_cast<const float4*>(base + 4 * f);
      acc[4 * f + 0] += (double)v.x;
      acc[4 * f + 1] += (double)v.y;
      acc[4 * f + 2] += (double)v.z;
      acc[4 * f + 3] += (double)v.w;
    }
  }
  __syncthreads();
#pragma unroll
  for (int f = 0; f < 16; ++f) {
    const int j = jq * 16 + f;
    const double c2 = a2s[i] + b2s[j] - 2.0 * acc[f];
    costd[i * 64 + j] = sqrt(c2 > 0.0 ? c2 : 0.0);
  }
  __syncthreads();

  if (tid < 64) {
    const int l = tid;                 // lane l owns column j = l+1 (and row l+1 for u/colof)
    const double INFD = 1e30;
    const unsigned long long SGN = 0x8000000000000000ULL;

    // ---- column reduction init: v[j] = min_i c[i,j], greedy tight matching
    double cmin = costd[l];
    int cargmin = 0;
#pragma unroll 8
    for (int r = 1; r < 64; ++r) {
      const double cv = costd[r * 64 + l];
      if (cv < cmin) { cmin = cv; cargmin = r; }
    }
    double v_l = cmin;                 // v[l+1]
    double u_l = 0.0;                  // u[l+1]
    int p_l = 0;                       // p[l+1]  (row matched to column l+1)
    int colof_l = 0;                   // column matched to row l+1 (0 = unmatched)
    unsigned long long rowused = 0ULL; // uniform: rows matched at init
    for (int j = 0; j < 64; ++j) {
      const int rj = __builtin_amdgcn_readlane(cargmin, j);
      if (!((rowused >> rj) & 1ULL)) {
        rowused |= 1ULL << rj;
        if (l == j) p_l = rj + 1;
        if (l == rj) colof_l = j + 1;
      }
    }

    // ---- shortest augmenting path for each remaining free row
    for (int i_row = 1; i_row <= 64; ++i_row) {
      if ((rowused >> (i_row - 1)) & 1ULL) continue;
      double minv = INFD;
      int way_l = 0;
      bool used = false;
      int j0 = 0;

      while (true) {
        const int i0 = (j0 == 0) ? i_row : __builtin_amdgcn_readlane(p_l, j0 - 1);
        if (i0 == 0) break;            // column j0 is free -> augment
        if (j0 > 0 && l == j0 - 1) used = true;
        const double ui0 = readlane_d(u_l, i0 - 1);
        const double cur = costd[(i0 - 1) * 64 + l] - ui0 - v_l;
        if (!used && cur < minv) { minv = cur; way_l = j0; }
        const double cand = used ? INFD : minv;

        // exact min via monotone-u64 key, VALU-only DPP reduce to lane 63
        const unsigned long long cb = (unsigned long long)__double_as_longlong(cand);
        const unsigned long long key =
            cb ^ ((unsigned long long)((long long)cb >> 63) | SGN);
        unsigned long long r = key;
        r = dpp_min_step<0x111, 0xf>(r);   // row_shr:1
        r = dpp_min_step<0x112, 0xf>(r);   // row_shr:2
        r = dpp_min_step<0x114, 0xf>(r);   // row_shr:4
        r = dpp_min_step<0x118, 0xf>(r);   // row_shr:8
        r = dpp_min_step<0x142, 0xa>(r);   // row_bcast:15 (rows 1,3)
        r = dpp_min_step<0x143, 0xc>(r);   // row_bcast:31 (rows 2,3)
        const unsigned mhi = (unsigned)__builtin_amdgcn_readlane((int)(unsigned)(r >> 32), 63);
        const unsigned mlo = (unsigned)__builtin_amdgcn_readlane((int)(unsigned)r, 63);
        const unsigned long long mkey = ((unsigned long long)mhi << 32) | mlo;
        const unsigned long long mbits = (mkey & SGN) ? (mkey ^ SGN) : ~mkey;
        const double delta = __longlong_as_double((long long)mbits);

        const unsigned long long eqm = __ballot(key == mkey);
        const int jmin = __ffsll(eqm) - 1;      // first-index tie-break == argmin

        if (used) v_l -= delta; else minv -= delta;
        const unsigned long long um = __ballot(used);
        // u[p[j]] += delta for used j (incl. j=0: p[0]=i_row). Row r=l+1 is hit iff
        // r == i_row, or r is matched to a used column (colof_l bit set in um).
        const bool addu = (l + 1 == i_row) ||
                          (colof_l != 0 && ((um >> (colof_l - 1)) & 1ULL));
        if (addu) u_l += delta;
        j0 = jmin + 1;
      }

      // augment along alternating path (j0 points at a free column)
      while (j0 != 0) {
        const int j1 = __builtin_amdgcn_readlane(way_l, j0 - 1);
        const int pj1 = (j1 == 0) ? i_row : __builtin_amdgcn_readlane(p_l, j1 - 1);
        if (l == j0 - 1) p_l = pj1;    // p[j0] = p[j1]
        if (l == pj1 - 1) colof_l = j0;// row pj1 now matched to column j0
        j0 = j1;
      }
    }

    out[b * NK + l] = l;                       // inds  (arange)
    out[NB * NK + b * NK + l] = colof_l - 1;   // inds2 (col of row l+1), coalesced
  }
}

extern "C" void kernel_launch(void* const* d_in, const int* in_sizes, int n_in,
                              void* d_out, int out_size, void* d_ws, size_t ws_size,
                              hipStream_t stream) {
  const float* A = (const float*)d_in[0];   // outputs [16,64,50176] fp32
  const float* B = (const float*)d_in[1];   // targets [16,64,50176] fp32
  float* ws = (float*)d_ws;                 // needs ~12.7 MiB
  int* out = (int*)d_out;                   // 2048 int32: [inds | inds2]

  dim3 g1(NSPLIT, NB);
  gemm_partial<<<g1, 64, 0, stream>>>(A, B, ws);
  reduce_lsa<<<NB, 256, 0, stream>>>(ws, out);
}

// Round 5
// 389.686 us; speedup vs baseline: 2.9908x; 1.3120x over previous
//
#include <hip/hip_runtime.h>

#define DD 50176          // h*w
#define NB 16             // batches
#define NK 64             // k masks
#define NSPLIT 49         // K-splits per batch
#define NTILE 16          // 64-wide k-tiles per split  (49*16*64 = 50176)
#define TK 64

// workspace layout (float elements)
#define PAB_OFF  0
#define PAB_SIZE ((size_t)NB * NSPLIT * 4096)
#define PA2_OFF  PAB_SIZE
#define PA2_SIZE ((size_t)NB * NSPLIT * 64)
#define PB2_OFF  (PA2_OFF + PA2_SIZE)

// ---------------------------------------------------------------------------
// Kernel 1: split-K partial GEMM, 256 threads, 4x4 register tile/thread.
// T14 register double-buffer: tile t+1's global loads issue right after the
// LDS-write barrier and drain under tile t's compute. Norms accumulate from
// the staging registers (once per tile), keeping the kk-loop pure FMA+ds_read.
// LDS transposed [kk][col] with granule skew col=(row+4*(kk>>2))&63: staging
// ds_write and fragment ds_read_b128 are both <=2-way bank conflicts.
// ---------------------------------------------------------------------------
__global__ __launch_bounds__(256) void gemm_partial(const float* __restrict__ A,
                                                    const float* __restrict__ B,
                                                    float* __restrict__ ws) {
  const int s = blockIdx.x;     // split
  const int b = blockIdx.y;     // batch
  const float* Ab = A + (size_t)b * NK * DD;
  const float* Bb = B + (size_t)b * NK * DD;
  __shared__ float As[TK * 64];
  __shared__ float Bs[TK * 64];
  const int tid = threadIdx.x;
  const int ti = tid & 15;      // output row-quad
  const int tj = tid >> 4;      // output col-quad
  const int kq = tid & 15;      // staging: k-granule 0..15
  const int r0 = tid >> 4;      // staging: row base 0..15

  float c[4][4] = {{0.f, 0.f, 0.f, 0.f}, {0.f, 0.f, 0.f, 0.f},
                   {0.f, 0.f, 0.f, 0.f}, {0.f, 0.f, 0.f, 0.f}};
  float a2p[4] = {0.f, 0.f, 0.f, 0.f};   // norm partials for rows f*16+r0
  float b2p[4] = {0.f, 0.f, 0.f, 0.f};
  float4 avr[4], bvr[4];

  // prologue: load tile 0 into registers
  {
    const int k0 = s * NTILE * TK;
#pragma unroll
    for (int f = 0; f < 4; ++f) {
      const int r = f * 16 + r0;
      avr[f] = *reinterpret_cast<const float4*>(Ab + (size_t)r * DD + k0 + kq * 4);
      bvr[f] = *reinterpret_cast<const float4*>(Bb + (size_t)r * DD + k0 + kq * 4);
    }
  }

  for (int t = 0; t < NTILE; ++t) {
    __syncthreads();            // all waves done reading LDS of tile t-1
#pragma unroll
    for (int f = 0; f < 4; ++f) {
      const int r = f * 16 + r0;
      const int col = (r + 4 * kq) & 63;
      const float4 av = avr[f];
      const float4 bv = bvr[f];
      As[(kq * 4 + 0) * 64 + col] = av.x;
      As[(kq * 4 + 1) * 64 + col] = av.y;
      As[(kq * 4 + 2) * 64 + col] = av.z;
      As[(kq * 4 + 3) * 64 + col] = av.w;
      Bs[(kq * 4 + 0) * 64 + col] = bv.x;
      Bs[(kq * 4 + 1) * 64 + col] = bv.y;
      Bs[(kq * 4 + 2) * 64 + col] = bv.z;
      Bs[(kq * 4 + 3) * 64 + col] = bv.w;
      // norms from registers (rows f*16+r0, k-cols 4kq..4kq+3 of this tile)
      a2p[f] = fmaf(av.x, av.x, a2p[f]); a2p[f] = fmaf(av.y, av.y, a2p[f]);
      a2p[f] = fmaf(av.z, av.z, a2p[f]); a2p[f] = fmaf(av.w, av.w, a2p[f]);
      b2p[f] = fmaf(bv.x, bv.x, b2p[f]); b2p[f] = fmaf(bv.y, bv.y, b2p[f]);
      b2p[f] = fmaf(bv.z, bv.z, b2p[f]); b2p[f] = fmaf(bv.w, bv.w, b2p[f]);
    }
    __syncthreads();            // tile t staged

    if (t + 1 < NTILE) {        // issue next tile's loads; drain under compute
      const int k0 = (s * NTILE + t + 1) * TK;
#pragma unroll
      for (int f = 0; f < 4; ++f) {
        const int r = f * 16 + r0;
        avr[f] = *reinterpret_cast<const float4*>(Ab + (size_t)r * DD + k0 + kq * 4);
        bvr[f] = *reinterpret_cast<const float4*>(Bb + (size_t)r * DD + k0 + kq * 4);
      }
    }

#pragma unroll 8
    for (int kk = 0; kk < TK; ++kk) {
      const int g = 4 * (kk >> 2);
      const float4 a4 = *reinterpret_cast<const float4*>(&As[kk * 64 + ((4 * ti + g) & 63)]);
      const float4 b4 = *reinterpret_cast<const float4*>(&Bs[kk * 64 + ((4 * tj + g) & 63)]);
      const float ar[4] = {a4.x, a4.y, a4.z, a4.w};
      const float br[4] = {b4.x, b4.y, b4.z, b4.w};
#pragma unroll
      for (int r = 0; r < 4; ++r)
#pragma unroll
        for (int cc = 0; cc < 4; ++cc)
          c[r][cc] = fmaf(ar[r], br[cc], c[r][cc]);
    }
  }

  float* Pab = ws + PAB_OFF + (size_t)(b * NSPLIT + s) * 4096;
#pragma unroll
  for (int r = 0; r < 4; ++r) {
    *reinterpret_cast<float4*>(Pab + (ti * 4 + r) * 64 + tj * 4) =
        make_float4(c[r][0], c[r][1], c[r][2], c[r][3]);
  }

  // reduce norm partials across the 16 kq lanes of each 16-lane group
#pragma unroll
  for (int f = 0; f < 4; ++f) {
#pragma unroll
    for (int off = 1; off < 16; off <<= 1) {
      a2p[f] += __shfl_xor(a2p[f], off, 64);
      b2p[f] += __shfl_xor(b2p[f], off, 64);
    }
  }
  if (kq == 0) {
    float* Pa2 = ws + PA2_OFF + (size_t)(b * NSPLIT + s) * 64;
    float* Pb2 = ws + PB2_OFF + (size_t)(b * NSPLIT + s) * 64;
#pragma unroll
    for (int f = 0; f < 4; ++f) {
      Pa2[f * 16 + r0] = a2p[f];
      Pb2[f * 16 + r0] = b2p[f];
    }
  }
}

// ---------------------------------------------------------------------------
// Kernel 2: per batch — reduce partials in double, build cost, exact JV LSA
// with column-reduction init (v[j]=colmin, greedy tight matching, u=0) and
// register-resident Dijkstra (DPP u64-key min) for the remaining free rows.
// ---------------------------------------------------------------------------
__device__ __forceinline__ double readlane_d(double x, int lane) {
  const int lo = __builtin_amdgcn_readlane(__double2loint(x), lane);
  const int hi = __builtin_amdgcn_readlane(__double2hiint(x), lane);
  return __hiloint2double(hi, lo);
}

template <int CTRL, int RMASK>
__device__ __forceinline__ unsigned long long dpp_min_step(unsigned long long k) {
  const unsigned ohi = (unsigned)__builtin_amdgcn_update_dpp(
      -1, (int)(unsigned)(k >> 32), CTRL, RMASK, 0xf, false);
  const unsigned olo = (unsigned)__builtin_amdgcn_update_dpp(
      -1, (int)(unsigned)k, CTRL, RMASK, 0xf, false);
  const unsigned long long o = ((unsigned long long)ohi << 32) | olo;
  return o < k ? o : k;
}

__global__ __launch_bounds__(256) void reduce_lsa(const float* __restrict__ ws,
                                                  int* __restrict__ out) {
  const int b = blockIdx.x;
  __shared__ double costd[64 * 64];
  __shared__ double a2s[64];
  __shared__ double b2s[64];
  const int tid = threadIdx.x;

  // reduce norms (deterministic fixed-order sums)
  if (tid < 64) {
    double sum = 0.0;
    for (int sp = 0; sp < NSPLIT; ++sp)
      sum += (double)ws[PA2_OFF + (size_t)(b * NSPLIT + sp) * 64 + tid];
    a2s[tid] = sum;
  }
  if (tid >= 64 && tid < 128) {
    const int l = tid - 64;
    double sum = 0.0;
    for (int sp = 0; sp < NSPLIT; ++sp)
      sum += (double)ws[PB2_OFF + (size_t)(b * NSPLIT + sp) * 64 + l];
    b2s[l] = sum;
  }

  // reduce ab partials: thread -> (row i, 16 cols)
  const int i = tid >> 2;
  const int jq = tid & 3;
  double acc[16];
#pragma unroll
  for (int f = 0; f < 16; ++f) acc[f] = 0.0;
  for (int sp = 0; sp < NSPLIT; ++sp) {
    const float* base = ws + PAB_OFF + (size_t)(b * NSPLIT + sp) * 4096 + i * 64 + jq * 16;
#pragma unroll
    for (int f = 0; f < 4; ++f) {
      const float4 v = *reinterpret_cast<const float4*>(base + 4 * f);
      acc[4 * f + 0] += (double)v.x;
      acc[4 * f + 1] += (double)v.y;
      acc[4 * f + 2] += (double)v.z;
      acc[4 * f + 3] += (double)v.w;
    }
  }
  __syncthreads();
#pragma unroll
  for (int f = 0; f < 16; ++f) {
    const int j = jq * 16 + f;
    const double c2 = a2s[i] + b2s[j] - 2.0 * acc[f];
    costd[i * 64 + j] = sqrt(c2 > 0.0 ? c2 : 0.0);
  }
  __syncthreads();

  if (tid < 64) {
    const int l = tid;                 // lane l owns column j = l+1 (and row l+1 for u/colof)
    const double INFD = 1e30;
    const unsigned long long SGN = 0x8000000000000000ULL;

    // ---- column reduction init: v[j] = min_i c[i,j], greedy tight matching
    double cmin = costd[l];
    int cargmin = 0;
#pragma unroll 8
    for (int r = 1; r < 64; ++r) {
      const double cv = costd[r * 64 + l];
      if (cv < cmin) { cmin = cv; cargmin = r; }
    }
    double v_l = cmin;                 // v[l+1]
    double u_l = 0.0;                  // u[l+1]
    int p_l = 0;                       // p[l+1]  (row matched to column l+1)
    int colof_l = 0;                   // column matched to row l+1 (0 = unmatched)
    unsigned long long rowused = 0ULL; // uniform: rows matched at init
    for (int j = 0; j < 64; ++j) {
      const int rj = __builtin_amdgcn_readlane(cargmin, j);
      if (!((rowused >> rj) & 1ULL)) {
        rowused |= 1ULL << rj;
        if (l == j) p_l = rj + 1;
        if (l == rj) colof_l = j + 1;
      }
    }

    // ---- shortest augmenting path for each remaining free row
    for (int i_row = 1; i_row <= 64; ++i_row) {
      if ((rowused >> (i_row - 1)) & 1ULL) continue;
      double minv = INFD;
      int way_l = 0;
      bool used = false;
      int j0 = 0;

      while (true) {
        const int i0 = (j0 == 0) ? i_row : __builtin_amdgcn_readlane(p_l, j0 - 1);
        if (i0 == 0) break;            // column j0 is free -> augment
        if (j0 > 0 && l == j0 - 1) used = true;
        const double ui0 = readlane_d(u_l, i0 - 1);
        const double cur = costd[(i0 - 1) * 64 + l] - ui0 - v_l;
        if (!used && cur < minv) { minv = cur; way_l = j0; }
        const double cand = used ? INFD : minv;

        // exact min via monotone-u64 key, VALU-only DPP reduce to lane 63
        const unsigned long long cb = (unsigned long long)__double_as_longlong(cand);
        const unsigned long long key =
            cb ^ ((unsigned long long)((long long)cb >> 63) | SGN);
        unsigned long long r = key;
        r = dpp_min_step<0x111, 0xf>(r);   // row_shr:1
        r = dpp_min_step<0x112, 0xf>(r);   // row_shr:2
        r = dpp_min_step<0x114, 0xf>(r);   // row_shr:4
        r = dpp_min_step<0x118, 0xf>(r);   // row_shr:8
        r = dpp_min_step<0x142, 0xa>(r);   // row_bcast:15 (rows 1,3)
        r = dpp_min_step<0x143, 0xc>(r);   // row_bcast:31 (rows 2,3)
        const unsigned mhi = (unsigned)__builtin_amdgcn_readlane((int)(unsigned)(r >> 32), 63);
        const unsigned mlo = (unsigned)__builtin_amdgcn_readlane((int)(unsigned)r, 63);
        const unsigned long long mkey = ((unsigned long long)mhi << 32) | mlo;
        const unsigned long long mbits = (mkey & SGN) ? (mkey ^ SGN) : ~mkey;
        const double delta = __longlong_as_double((long long)mbits);

        const unsigned long long eqm = __ballot(key == mkey);
        const int jmin = __ffsll(eqm) - 1;      // first-index tie-break == argmin

        if (used) v_l -= delta; else minv -= delta;
        const unsigned long long um = __ballot(used);
        // u[p[j]] += delta for used j (incl. j=0: p[0]=i_row). Row r=l+1 is hit iff
        // r == i_row, or r is matched to a used column (colof_l bit set in um).
        const bool addu = (l + 1 == i_row) ||
                          (colof_l != 0 && ((um >> (colof_l - 1)) & 1ULL));
        if (addu) u_l += delta;
        j0 = jmin + 1;
      }

      // augment along alternating path (j0 points at a free column)
      while (j0 != 0) {
        const int j1 = __builtin_amdgcn_readlane(way_l, j0 - 1);
        const int pj1 = (j1 == 0) ? i_row : __builtin_amdgcn_readlane(p_l, j1 - 1);
        if (l == j0 - 1) p_l = pj1;    // p[j0] = p[j1]
        if (l == pj1 - 1) colof_l = j0;// row pj1 now matched to column j0
        j0 = j1;
      }
    }

    out[b * NK + l] = l;                       // inds  (arange)
    out[NB * NK + b * NK + l] = colof_l - 1;   // inds2 (col of row l+1), coalesced
  }
}

extern "C" void kernel_launch(void* const* d_in, const int* in_sizes, int n_in,
                              void* d_out, int out_size, void* d_ws, size_t ws_size,
                              hipStream_t stream) {
  const float* A = (const float*)d_in[0];   // outputs [16,64,50176] fp32
  const float* B = (const float*)d_in[1];   // targets [16,64,50176] fp32
  float* ws = (float*)d_ws;                 // needs ~12.7 MiB
  int* out = (int*)d_out;                   // 2048 int32: [inds | inds2]

  dim3 g1(NSPLIT, NB);
  gemm_partial<<<g1, 256, 0, stream>>>(A, B, ws);
  reduce_lsa<<<NB, 256, 0, stream>>>(ws, out);
}

// Round 6
// 382.000 us; speedup vs baseline: 3.0510x; 1.0201x over previous
//
#include <hip/hip_runtime.h>

#define DD 50176          // h*w
#define NB 16             // batches
#define NK 64             // k masks
#define TK 64             // k-tile width

// ---------------------------------------------------------------------------
// Kernel 1: split-K partial GEMM, 256 threads, 4x4 register tile/thread.
// T14 register double-buffer; norms accumulated from staging registers.
// LDS transposed [kk][col] with granule skew col=(row+4*(kk>>2))&63.
// Templated on split count: NSPLIT=112 (7 blocks/CU) when ws allows, else 49.
// ---------------------------------------------------------------------------
template <int NSPLIT, int NTILE>
__global__ __launch_bounds__(256) void gemm_partial(const float* __restrict__ A,
                                                    const float* __restrict__ B,
                                                    float* __restrict__ ws) {
  const int s = blockIdx.x;     // split
  const int b = blockIdx.y;     // batch
  const float* Ab = A + (size_t)b * NK * DD;
  const float* Bb = B + (size_t)b * NK * DD;
  __shared__ float As[TK * 64];
  __shared__ float Bs[TK * 64];
  const int tid = threadIdx.x;
  const int ti = tid & 15;      // output row-quad
  const int tj = tid >> 4;      // output col-quad
  const int kq = tid & 15;      // staging: k-granule 0..15
  const int r0 = tid >> 4;      // staging: row base 0..15

  float c[4][4] = {{0.f, 0.f, 0.f, 0.f}, {0.f, 0.f, 0.f, 0.f},
                   {0.f, 0.f, 0.f, 0.f}, {0.f, 0.f, 0.f, 0.f}};
  float a2p[4] = {0.f, 0.f, 0.f, 0.f};
  float b2p[4] = {0.f, 0.f, 0.f, 0.f};
  float4 avr[4], bvr[4];

  {
    const int k0 = s * NTILE * TK;
#pragma unroll
    for (int f = 0; f < 4; ++f) {
      const int r = f * 16 + r0;
      avr[f] = *reinterpret_cast<const float4*>(Ab + (size_t)r * DD + k0 + kq * 4);
      bvr[f] = *reinterpret_cast<const float4*>(Bb + (size_t)r * DD + k0 + kq * 4);
    }
  }

  for (int t = 0; t < NTILE; ++t) {
    __syncthreads();
#pragma unroll
    for (int f = 0; f < 4; ++f) {
      const int r = f * 16 + r0;
      const int col = (r + 4 * kq) & 63;
      const float4 av = avr[f];
      const float4 bv = bvr[f];
      As[(kq * 4 + 0) * 64 + col] = av.x;
      As[(kq * 4 + 1) * 64 + col] = av.y;
      As[(kq * 4 + 2) * 64 + col] = av.z;
      As[(kq * 4 + 3) * 64 + col] = av.w;
      Bs[(kq * 4 + 0) * 64 + col] = bv.x;
      Bs[(kq * 4 + 1) * 64 + col] = bv.y;
      Bs[(kq * 4 + 2) * 64 + col] = bv.z;
      Bs[(kq * 4 + 3) * 64 + col] = bv.w;
      a2p[f] = fmaf(av.x, av.x, a2p[f]); a2p[f] = fmaf(av.y, av.y, a2p[f]);
      a2p[f] = fmaf(av.z, av.z, a2p[f]); a2p[f] = fmaf(av.w, av.w, a2p[f]);
      b2p[f] = fmaf(bv.x, bv.x, b2p[f]); b2p[f] = fmaf(bv.y, bv.y, b2p[f]);
      b2p[f] = fmaf(bv.z, bv.z, b2p[f]); b2p[f] = fmaf(bv.w, bv.w, b2p[f]);
    }
    __syncthreads();

    if (t + 1 < NTILE) {
      const int k0 = (s * NTILE + t + 1) * TK;
#pragma unroll
      for (int f = 0; f < 4; ++f) {
        const int r = f * 16 + r0;
        avr[f] = *reinterpret_cast<const float4*>(Ab + (size_t)r * DD + k0 + kq * 4);
        bvr[f] = *reinterpret_cast<const float4*>(Bb + (size_t)r * DD + k0 + kq * 4);
      }
    }

#pragma unroll 8
    for (int kk = 0; kk < TK; ++kk) {
      const int g = 4 * (kk >> 2);
      const float4 a4 = *reinterpret_cast<const float4*>(&As[kk * 64 + ((4 * ti + g) & 63)]);
      const float4 b4 = *reinterpret_cast<const float4*>(&Bs[kk * 64 + ((4 * tj + g) & 63)]);
      const float ar[4] = {a4.x, a4.y, a4.z, a4.w};
      const float br[4] = {b4.x, b4.y, b4.z, b4.w};
#pragma unroll
      for (int r = 0; r < 4; ++r)
#pragma unroll
        for (int cc = 0; cc < 4; ++cc)
          c[r][cc] = fmaf(ar[r], br[cc], c[r][cc]);
    }
  }

  float* Pab = ws + (size_t)(b * NSPLIT + s) * 4096;
#pragma unroll
  for (int r = 0; r < 4; ++r) {
    *reinterpret_cast<float4*>(Pab + (ti * 4 + r) * 64 + tj * 4) =
        make_float4(c[r][0], c[r][1], c[r][2], c[r][3]);
  }

#pragma unroll
  for (int f = 0; f < 4; ++f) {
#pragma unroll
    for (int off = 1; off < 16; off <<= 1) {
      a2p[f] += __shfl_xor(a2p[f], off, 64);
      b2p[f] += __shfl_xor(b2p[f], off, 64);
    }
  }
  if (kq == 0) {
    float* Pa2 = ws + (size_t)NB * NSPLIT * 4096 + (size_t)(b * NSPLIT + s) * 64;
    float* Pb2 = Pa2 + (size_t)NB * NSPLIT * 64;
#pragma unroll
    for (int f = 0; f < 4; ++f) {
      Pa2[f * 16 + r0] = a2p[f];
      Pb2[f * 16 + r0] = b2p[f];
    }
  }
}

// ---------------------------------------------------------------------------
// Kernel 2: reduce partials in double, build cost, exact JV LSA:
// col-reduction init + greedy, Augmenting Row Reduction (kick-chains, dual
// transfer), then register-resident Dijkstra for the few remaining rows.
// All comparisons via monotone-u64 keys; first-index tie-break throughout.
// ---------------------------------------------------------------------------
__device__ __forceinline__ double readlane_d(double x, int lane) {
  const int lo = __builtin_amdgcn_readlane(__double2loint(x), lane);
  const int hi = __builtin_amdgcn_readlane(__double2hiint(x), lane);
  return __hiloint2double(hi, lo);
}

template <int CTRL, int RMASK>
__device__ __forceinline__ unsigned long long dpp_min_step(unsigned long long k) {
  const unsigned ohi = (unsigned)__builtin_amdgcn_update_dpp(
      -1, (int)(unsigned)(k >> 32), CTRL, RMASK, 0xf, false);
  const unsigned olo = (unsigned)__builtin_amdgcn_update_dpp(
      -1, (int)(unsigned)k, CTRL, RMASK, 0xf, false);
  const unsigned long long o = ((unsigned long long)ohi << 32) | olo;
  return o < k ? o : k;
}

__device__ __forceinline__ unsigned long long pack_key(double x) {
  const unsigned long long cb = (unsigned long long)__double_as_longlong(x);
  return cb ^ ((unsigned long long)((long long)cb >> 63) | 0x8000000000000000ULL);
}
__device__ __forceinline__ double unpack_key(unsigned long long k) {
  const unsigned long long SGN = 0x8000000000000000ULL;
  const unsigned long long mbits = (k & SGN) ? (k ^ SGN) : ~k;
  return __longlong_as_double((long long)mbits);
}
// min over 64 lanes -> broadcast (uniform) result
__device__ __forceinline__ unsigned long long dpp_min64(unsigned long long k) {
  k = dpp_min_step<0x111, 0xf>(k);   // row_shr:1
  k = dpp_min_step<0x112, 0xf>(k);   // row_shr:2
  k = dpp_min_step<0x114, 0xf>(k);   // row_shr:4
  k = dpp_min_step<0x118, 0xf>(k);   // row_shr:8
  k = dpp_min_step<0x142, 0xa>(k);   // row_bcast:15
  k = dpp_min_step<0x143, 0xc>(k);   // row_bcast:31
  const unsigned hi = (unsigned)__builtin_amdgcn_readlane((int)(unsigned)(k >> 32), 63);
  const unsigned lo = (unsigned)__builtin_amdgcn_readlane((int)(unsigned)k, 63);
  return ((unsigned long long)hi << 32) | lo;
}

__global__ __launch_bounds__(256) void reduce_lsa(const float* __restrict__ ws,
                                                  int* __restrict__ out,
                                                  int nsplit) {
  const int b = blockIdx.x;
  __shared__ double costd[64 * 64];
  __shared__ double a2s[64];
  __shared__ double b2s[64];
  const int tid = threadIdx.x;
  const size_t pa2_off = (size_t)NB * nsplit * 4096;
  const size_t pb2_off = pa2_off + (size_t)NB * nsplit * 64;

  if (tid < 64) {
    double sum = 0.0;
    for (int sp = 0; sp < nsplit; ++sp)
      sum += (double)ws[pa2_off + (size_t)(b * nsplit + sp) * 64 + tid];
    a2s[tid] = sum;
  }
  if (tid >= 64 && tid < 128) {
    const int l = tid - 64;
    double sum = 0.0;
    for (int sp = 0; sp < nsplit; ++sp)
      sum += (double)ws[pb2_off + (size_t)(b * nsplit + sp) * 64 + l];
    b2s[l] = sum;
  }

  const int i = tid >> 2;
  const int jq = tid & 3;
  double acc[16];
#pragma unroll
  for (int f = 0; f < 16; ++f) acc[f] = 0.0;
  for (int sp = 0; sp < nsplit; ++sp) {
    const float* base = ws + (size_t)(b * nsplit + sp) * 4096 + i * 64 + jq * 16;
#pragma unroll
    for (int f = 0; f < 4; ++f) {
      const float4 v = *reinterpret_cast<const float4*>(base + 4 * f);
      acc[4 * f + 0] += (double)v.x;
      acc[4 * f + 1] += (double)v.y;
      acc[4 * f + 2] += (double)v.z;
      acc[4 * f + 3] += (double)v.w;
    }
  }
  __syncthreads();
#pragma unroll
  for (int f = 0; f < 16; ++f) {
    const int j = jq * 16 + f;
    const double c2 = a2s[i] + b2s[j] - 2.0 * acc[f];
    costd[i * 64 + j] = sqrt(c2 > 0.0 ? c2 : 0.0);
  }
  __syncthreads();

  if (tid < 64) {
    const int l = tid;                 // lane l <-> column l+1, row l+1
    const double INFD = 1e30;

    // ---- column reduction: v[j] = min_i c[i,j]; greedy tight matching, u=0
    double cmin = costd[l];
    int cargmin = 0;
#pragma unroll 8
    for (int r = 1; r < 64; ++r) {
      const double cv = costd[r * 64 + l];
      if (cv < cmin) { cmin = cv; cargmin = r; }
    }
    double v_l = cmin;
    double u_l = 0.0;
    int p_l = 0;                       // row matched to column l+1 (0 = free)
    int colof_l = 0;                   // column matched to row l+1 (0 = free)
    unsigned long long rowused = 0ULL;
    for (int j = 0; j < 64; ++j) {
      const int rj = __builtin_amdgcn_readlane(cargmin, j);
      if (!((rowused >> rj) & 1ULL)) {
        rowused |= 1ULL << rj;
        if (l == j) p_l = rj + 1;
        if (l == rj) colof_l = j + 1;
      }
    }
    unsigned long long freemask = ~rowused;  // bit r-1 = row r unassigned

    // ---- Augmenting Row Reduction (JV): resolve most free rows cheaply.
    // Maintains dual feasibility + tight matched edges (exactness preserved).
    for (int pass = 0; pass < 2; ++pass) {
      unsigned long long m = freemask;
      while (m) {
        int ir = __ffsll(m);           // 1-indexed free row
        m &= m - 1;
        for (int chain = 0; chain < 8; ++chain) {
          if (!((freemask >> (ir - 1)) & 1ULL)) break;
          const double cur = costd[(ir - 1) * 64 + l] - v_l;
          const unsigned long long key1 = pack_key(cur);
          const unsigned long long mk1 = dpp_min64(key1);
          const double u1 = unpack_key(mk1);
          const int j1 = __ffsll(__ballot(key1 == mk1)) - 1;
          const unsigned long long key2 = (l == j1) ? pack_key(INFD) : key1;
          const unsigned long long mk2 = dpp_min64(key2);
          const double u2 = unpack_key(mk2);
          if (l == ir - 1) u_l = u2;
          const bool strict = (u1 < u2);
          if (strict && l == j1) v_l -= (u2 - u1);
          const int k = __builtin_amdgcn_readlane(p_l, j1);  // occupant of col j1
          if (strict || k == 0) {
            if (l == j1) p_l = ir;
            if (l == ir - 1) colof_l = j1 + 1;
            freemask &= ~(1ULL << (ir - 1));
            if (k != 0) {
              if (l == k - 1) colof_l = 0;
              freemask |= 1ULL << (k - 1);
              if (strict) { ir = k; continue; }  // retry kicked row
            }
            break;
          } else {
            break;                     // tie & occupied: leave for Dijkstra
          }
        }
      }
    }

    // ---- shortest augmenting path for remaining free rows
    for (int i_row = 1; i_row <= 64; ++i_row) {
      if (!((freemask >> (i_row - 1)) & 1ULL)) continue;
      double minv = INFD;
      int way_l = 0;
      bool used = false;
      int j0 = 0;

      while (true) {
        const int i0 = (j0 == 0) ? i_row : __builtin_amdgcn_readlane(p_l, j0 - 1);
        if (i0 == 0) break;
        if (j0 > 0 && l == j0 - 1) used = true;
        const double ui0 = readlane_d(u_l, i0 - 1);
        const double cur = costd[(i0 - 1) * 64 + l] - ui0 - v_l;
        if (!used && cur < minv) { minv = cur; way_l = j0; }
        const double cand = used ? INFD : minv;

        const unsigned long long key = pack_key(cand);
        const unsigned long long mkey = dpp_min64(key);
        const double delta = unpack_key(mkey);
        const int jmin = __ffsll(__ballot(key == mkey)) - 1;

        if (used) v_l -= delta; else minv -= delta;
        const unsigned long long um = __ballot(used);
        const bool addu = (l + 1 == i_row) ||
                          (colof_l != 0 && ((um >> (colof_l - 1)) & 1ULL));
        if (addu) u_l += delta;
        j0 = jmin + 1;
      }

      while (j0 != 0) {
        const int j1 = __builtin_amdgcn_readlane(way_l, j0 - 1);
        const int pj1 = (j1 == 0) ? i_row : __builtin_amdgcn_readlane(p_l, j1 - 1);
        if (l == j0 - 1) p_l = pj1;
        if (l == pj1 - 1) colof_l = j0;
        j0 = j1;
      }
    }

    out[b * NK + l] = l;                       // inds  (arange)
    out[NB * NK + b * NK + l] = colof_l - 1;   // inds2 (col of row l+1)
  }
}

extern "C" void kernel_launch(void* const* d_in, const int* in_sizes, int n_in,
                              void* d_out, int out_size, void* d_ws, size_t ws_size,
                              hipStream_t stream) {
  const float* A = (const float*)d_in[0];   // outputs [16,64,50176] fp32
  const float* B = (const float*)d_in[1];   // targets [16,64,50176] fp32
  float* ws = (float*)d_ws;
  int* out = (int*)d_out;                   // 2048 int32: [inds | inds2]

  // NSPLIT=112 needs (16*112*4096 + 2*16*112*64)*4 B ≈ 30.3 MB of ws.
  const size_t need112 = ((size_t)NB * 112 * 4096 + 2 * (size_t)NB * 112 * 64) * 4;
  if (ws_size >= need112) {
    gemm_partial<112, 7><<<dim3(112, NB), 256, 0, stream>>>(A, B, ws);
    reduce_lsa<<<NB, 256, 0, stream>>>(ws, out, 112);
  } else {
    gemm_partial<49, 16><<<dim3(49, NB), 256, 0, stream>>>(A, B, ws);
    reduce_lsa<<<NB, 256, 0, stream>>>(ws, out, 49);
  }
}

// Round 7
// 341.128 us; speedup vs baseline: 3.4165x; 1.1198x over previous
//
#include <hip/hip_runtime.h>

#define DD 50176          // h*w
#define NB 16             // batches
#define NK 64             // k masks
#define TK 64             // k-tile width

// ---------------------------------------------------------------------------
// Kernel 1: split-K partial GEMM, 256 threads, 4x4 register tile/thread.
// T14 register double-buffer; norms accumulated from staging registers.
// LDS transposed [kk][col] with granule skew col=(row+4*(kk>>2))&63.
// ---------------------------------------------------------------------------
template <int NSPLIT, int NTILE>
__global__ __launch_bounds__(256) void gemm_partial(const float* __restrict__ A,
                                                    const float* __restrict__ B,
                                                    float* __restrict__ ws) {
  const int s = blockIdx.x;     // split
  const int b = blockIdx.y;     // batch
  const float* Ab = A + (size_t)b * NK * DD;
  const float* Bb = B + (size_t)b * NK * DD;
  __shared__ float As[TK * 64];
  __shared__ float Bs[TK * 64];
  const int tid = threadIdx.x;
  const int ti = tid & 15;      // output row-quad
  const int tj = tid >> 4;      // output col-quad
  const int kq = tid & 15;      // staging: k-granule 0..15
  const int r0 = tid >> 4;      // staging: row base 0..15

  float c[4][4] = {{0.f, 0.f, 0.f, 0.f}, {0.f, 0.f, 0.f, 0.f},
                   {0.f, 0.f, 0.f, 0.f}, {0.f, 0.f, 0.f, 0.f}};
  float a2p[4] = {0.f, 0.f, 0.f, 0.f};
  float b2p[4] = {0.f, 0.f, 0.f, 0.f};
  float4 avr[4], bvr[4];

  {
    const int k0 = s * NTILE * TK;
#pragma unroll
    for (int f = 0; f < 4; ++f) {
      const int r = f * 16 + r0;
      avr[f] = *reinterpret_cast<const float4*>(Ab + (size_t)r * DD + k0 + kq * 4);
      bvr[f] = *reinterpret_cast<const float4*>(Bb + (size_t)r * DD + k0 + kq * 4);
    }
  }

  for (int t = 0; t < NTILE; ++t) {
    __syncthreads();
#pragma unroll
    for (int f = 0; f < 4; ++f) {
      const int r = f * 16 + r0;
      const int col = (r + 4 * kq) & 63;
      const float4 av = avr[f];
      const float4 bv = bvr[f];
      As[(kq * 4 + 0) * 64 + col] = av.x;
      As[(kq * 4 + 1) * 64 + col] = av.y;
      As[(kq * 4 + 2) * 64 + col] = av.z;
      As[(kq * 4 + 3) * 64 + col] = av.w;
      Bs[(kq * 4 + 0) * 64 + col] = bv.x;
      Bs[(kq * 4 + 1) * 64 + col] = bv.y;
      Bs[(kq * 4 + 2) * 64 + col] = bv.z;
      Bs[(kq * 4 + 3) * 64 + col] = bv.w;
      a2p[f] = fmaf(av.x, av.x, a2p[f]); a2p[f] = fmaf(av.y, av.y, a2p[f]);
      a2p[f] = fmaf(av.z, av.z, a2p[f]); a2p[f] = fmaf(av.w, av.w, a2p[f]);
      b2p[f] = fmaf(bv.x, bv.x, b2p[f]); b2p[f] = fmaf(bv.y, bv.y, b2p[f]);
      b2p[f] = fmaf(bv.z, bv.z, b2p[f]); b2p[f] = fmaf(bv.w, bv.w, b2p[f]);
    }
    __syncthreads();

    if (t + 1 < NTILE) {
      const int k0 = (s * NTILE + t + 1) * TK;
#pragma unroll
      for (int f = 0; f < 4; ++f) {
        const int r = f * 16 + r0;
        avr[f] = *reinterpret_cast<const float4*>(Ab + (size_t)r * DD + k0 + kq * 4);
        bvr[f] = *reinterpret_cast<const float4*>(Bb + (size_t)r * DD + k0 + kq * 4);
      }
    }

#pragma unroll 8
    for (int kk = 0; kk < TK; ++kk) {
      const int g = 4 * (kk >> 2);
      const float4 a4 = *reinterpret_cast<const float4*>(&As[kk * 64 + ((4 * ti + g) & 63)]);
      const float4 b4 = *reinterpret_cast<const float4*>(&Bs[kk * 64 + ((4 * tj + g) & 63)]);
      const float ar[4] = {a4.x, a4.y, a4.z, a4.w};
      const float br[4] = {b4.x, b4.y, b4.z, b4.w};
#pragma unroll
      for (int r = 0; r < 4; ++r)
#pragma unroll
        for (int cc = 0; cc < 4; ++cc)
          c[r][cc] = fmaf(ar[r], br[cc], c[r][cc]);
    }
  }

  float* Pab = ws + (size_t)(b * NSPLIT + s) * 4096;
#pragma unroll
  for (int r = 0; r < 4; ++r) {
    *reinterpret_cast<float4*>(Pab + (ti * 4 + r) * 64 + tj * 4) =
        make_float4(c[r][0], c[r][1], c[r][2], c[r][3]);
  }

#pragma unroll
  for (int f = 0; f < 4; ++f) {
#pragma unroll
    for (int off = 1; off < 16; off <<= 1) {
      a2p[f] += __shfl_xor(a2p[f], off, 64);
      b2p[f] += __shfl_xor(b2p[f], off, 64);
    }
  }
  if (kq == 0) {
    float* Pa2 = ws + (size_t)NB * NSPLIT * 4096 + (size_t)(b * NSPLIT + s) * 64;
    float* Pb2 = Pa2 + (size_t)NB * NSPLIT * 64;
#pragma unroll
    for (int f = 0; f < 4; ++f) {
      Pa2[f * 16 + r0] = a2p[f];
      Pb2[f * 16 + r0] = b2p[f];
    }
  }
}

// ---------------------------------------------------------------------------
// Kernel 2: parallel cost build. 16 slices x 16 batches = 256 blocks; each
// block reduces 256 cost elements (4 rows x 64 cols) over NSPLIT partials
// (coalesced), adds norms, sqrt, writes double cost matrix to ws.
// ---------------------------------------------------------------------------
template <int NSPLIT>
__global__ __launch_bounds__(256) void reduce_cost(const float* __restrict__ ws,
                                                   double* __restrict__ costg) {
  const int slice = blockIdx.x;  // 0..15
  const int b = blockIdx.y;
  const int tid = threadIdx.x;
  __shared__ double a2s[4], b2s[64];
  const size_t pa2 = (size_t)NB * NSPLIT * 4096;
  const size_t pb2 = pa2 + (size_t)NB * NSPLIT * 64;

  if (tid < 64) {
    double s = 0.0;
    for (int sp = 0; sp < NSPLIT; ++sp)
      s += (double)ws[pb2 + (size_t)(b * NSPLIT + sp) * 64 + tid];
    b2s[tid] = s;
  } else if (tid < 68) {
    const int r = slice * 4 + (tid - 64);
    double s = 0.0;
    for (int sp = 0; sp < NSPLIT; ++sp)
      s += (double)ws[pa2 + (size_t)(b * NSPLIT + sp) * 64 + r];
    a2s[tid - 64] = s;
  }

  const int elem = slice * 256 + tid;   // 0..4095
  double acc = 0.0;
  for (int sp = 0; sp < NSPLIT; ++sp)
    acc += (double)ws[(size_t)(b * NSPLIT + sp) * 4096 + elem];
  __syncthreads();

  const int ii = tid >> 6;              // row within slice
  const int j = tid & 63;
  const double c2 = a2s[ii] + b2s[j] - 2.0 * acc;
  costg[(size_t)b * 4096 + elem] = sqrt(c2 > 0.0 ? c2 : 0.0);
}

// ---------------------------------------------------------------------------
// Kernel 3: pure solver. 16 blocks x 64 threads (1 wave). Cost in LDS.
// Col-reduction init + greedy, Augmenting Row Reduction, register Dijkstra.
// ---------------------------------------------------------------------------
__device__ __forceinline__ double readlane_d(double x, int lane) {
  const int lo = __builtin_amdgcn_readlane(__double2loint(x), lane);
  const int hi = __builtin_amdgcn_readlane(__double2hiint(x), lane);
  return __hiloint2double(hi, lo);
}

template <int CTRL, int RMASK>
__device__ __forceinline__ unsigned long long dpp_min_step(unsigned long long k) {
  const unsigned ohi = (unsigned)__builtin_amdgcn_update_dpp(
      -1, (int)(unsigned)(k >> 32), CTRL, RMASK, 0xf, false);
  const unsigned olo = (unsigned)__builtin_amdgcn_update_dpp(
      -1, (int)(unsigned)k, CTRL, RMASK, 0xf, false);
  const unsigned long long o = ((unsigned long long)ohi << 32) | olo;
  return o < k ? o : k;
}

__device__ __forceinline__ unsigned long long pack_key(double x) {
  const unsigned long long cb = (unsigned long long)__double_as_longlong(x);
  return cb ^ ((unsigned long long)((long long)cb >> 63) | 0x8000000000000000ULL);
}
__device__ __forceinline__ double unpack_key(unsigned long long k) {
  const unsigned long long SGN = 0x8000000000000000ULL;
  const unsigned long long mbits = (k & SGN) ? (k ^ SGN) : ~k;
  return __longlong_as_double((long long)mbits);
}
__device__ __forceinline__ unsigned long long dpp_min64(unsigned long long k) {
  k = dpp_min_step<0x111, 0xf>(k);   // row_shr:1
  k = dpp_min_step<0x112, 0xf>(k);   // row_shr:2
  k = dpp_min_step<0x114, 0xf>(k);   // row_shr:4
  k = dpp_min_step<0x118, 0xf>(k);   // row_shr:8
  k = dpp_min_step<0x142, 0xa>(k);   // row_bcast:15
  k = dpp_min_step<0x143, 0xc>(k);   // row_bcast:31
  const unsigned hi = (unsigned)__builtin_amdgcn_readlane((int)(unsigned)(k >> 32), 63);
  const unsigned lo = (unsigned)__builtin_amdgcn_readlane((int)(unsigned)k, 63);
  return ((unsigned long long)hi << 32) | lo;
}

__global__ __launch_bounds__(64) void lsa_solve(const double* __restrict__ costg,
                                                int* __restrict__ out) {
  const int b = blockIdx.x;
  __shared__ double costd[64 * 64];
  const int tid = threadIdx.x;

  for (int e = tid; e < 4096; e += 64)
    costd[e] = costg[(size_t)b * 4096 + e];
  __syncthreads();

  const int l = tid;                 // lane l <-> column l+1, row l+1
  const double INFD = 1e30;

  // ---- column reduction: v[j] = min_i c[i,j]; greedy tight matching, u=0
  double cmin = costd[l];
  int cargmin = 0;
#pragma unroll 8
  for (int r = 1; r < 64; ++r) {
    const double cv = costd[r * 64 + l];
    if (cv < cmin) { cmin = cv; cargmin = r; }
  }
  double v_l = cmin;
  double u_l = 0.0;
  int p_l = 0;                       // row matched to column l+1 (0 = free)
  int colof_l = 0;                   // column matched to row l+1 (0 = free)
  unsigned long long rowused = 0ULL;
  for (int j = 0; j < 64; ++j) {
    const int rj = __builtin_amdgcn_readlane(cargmin, j);
    if (!((rowused >> rj) & 1ULL)) {
      rowused |= 1ULL << rj;
      if (l == j) p_l = rj + 1;
      if (l == rj) colof_l = j + 1;
    }
  }
  unsigned long long freemask = ~rowused;  // bit r-1 = row r unassigned

  // ---- Augmenting Row Reduction (JV)
  for (int pass = 0; pass < 2; ++pass) {
    unsigned long long m = freemask;
    while (m) {
      int ir = __ffsll(m);           // 1-indexed free row
      m &= m - 1;
      for (int chain = 0; chain < 8; ++chain) {
        if (!((freemask >> (ir - 1)) & 1ULL)) break;
        const double cur = costd[(ir - 1) * 64 + l] - v_l;
        const unsigned long long key1 = pack_key(cur);
        const unsigned long long mk1 = dpp_min64(key1);
        const double u1 = unpack_key(mk1);
        const int j1 = __ffsll(__ballot(key1 == mk1)) - 1;
        const unsigned long long key2 = (l == j1) ? pack_key(INFD) : key1;
        const unsigned long long mk2 = dpp_min64(key2);
        const double u2 = unpack_key(mk2);
        if (l == ir - 1) u_l = u2;
        const bool strict = (u1 < u2);
        if (strict && l == j1) v_l -= (u2 - u1);
        const int k = __builtin_amdgcn_readlane(p_l, j1);  // occupant of col j1
        if (strict || k == 0) {
          if (l == j1) p_l = ir;
          if (l == ir - 1) colof_l = j1 + 1;
          freemask &= ~(1ULL << (ir - 1));
          if (k != 0) {
            if (l == k - 1) colof_l = 0;
            freemask |= 1ULL << (k - 1);
            if (strict) { ir = k; continue; }  // retry kicked row
          }
          break;
        } else {
          break;                     // tie & occupied: leave for Dijkstra
        }
      }
    }
  }

  // ---- shortest augmenting path for remaining free rows
  for (int i_row = 1; i_row <= 64; ++i_row) {
    if (!((freemask >> (i_row - 1)) & 1ULL)) continue;
    double minv = INFD;
    int way_l = 0;
    bool used = false;
    int j0 = 0;

    while (true) {
      const int i0 = (j0 == 0) ? i_row : __builtin_amdgcn_readlane(p_l, j0 - 1);
      if (i0 == 0) break;
      if (j0 > 0 && l == j0 - 1) used = true;
      const double ui0 = readlane_d(u_l, i0 - 1);
      const double cur = costd[(i0 - 1) * 64 + l] - ui0 - v_l;
      if (!used && cur < minv) { minv = cur; way_l = j0; }
      const double cand = used ? INFD : minv;

      const unsigned long long key = pack_key(cand);
      const unsigned long long mkey = dpp_min64(key);
      const double delta = unpack_key(mkey);
      const int jmin = __ffsll(__ballot(key == mkey)) - 1;

      if (used) v_l -= delta; else minv -= delta;
      const unsigned long long um = __ballot(used);
      const bool addu = (l + 1 == i_row) ||
                        (colof_l != 0 && ((um >> (colof_l - 1)) & 1ULL));
      if (addu) u_l += delta;
      j0 = jmin + 1;
    }

    while (j0 != 0) {
      const int j1 = __builtin_amdgcn_readlane(way_l, j0 - 1);
      const int pj1 = (j1 == 0) ? i_row : __builtin_amdgcn_readlane(p_l, j1 - 1);
      if (l == j0 - 1) p_l = pj1;
      if (l == pj1 - 1) colof_l = j0;
      j0 = j1;
    }
  }

  out[b * NK + l] = l;                       // inds  (arange)
  out[NB * NK + b * NK + l] = colof_l - 1;   // inds2 (col of row l+1)
}

extern "C" void kernel_launch(void* const* d_in, const int* in_sizes, int n_in,
                              void* d_out, int out_size, void* d_ws, size_t ws_size,
                              hipStream_t stream) {
  const float* A = (const float*)d_in[0];   // outputs [16,64,50176] fp32
  const float* B = (const float*)d_in[1];   // targets [16,64,50176] fp32
  float* ws = (float*)d_ws;
  int* out = (int*)d_out;                   // 2048 int32: [inds | inds2]

  // floats used by partials: NB*NSPLIT*(4096+128); cost doubles appended.
  const size_t f112 = (size_t)NB * 112 * 4224;
  const size_t need112 = f112 * 4 + (size_t)NB * 4096 * 8;
  const size_t f49 = (size_t)NB * 49 * 4224;
  const size_t need49 = f49 * 4 + (size_t)NB * 4096 * 8;

  if (ws_size >= need112) {
    double* costg = (double*)(ws + f112);
    gemm_partial<112, 7><<<dim3(112, NB), 256, 0, stream>>>(A, B, ws);
    reduce_cost<112><<<dim3(16, NB), 256, 0, stream>>>(ws, costg);
    lsa_solve<<<NB, 64, 0, stream>>>(costg, out);
  } else {
    double* costg = (double*)(ws + f49);
    gemm_partial<49, 16><<<dim3(49, NB), 256, 0, stream>>>(A, B, ws);
    reduce_cost<49><<<dim3(16, NB), 256, 0, stream>>>(ws, costg);
    lsa_solve<<<NB, 64, 0, stream>>>(costg, out);
  }
}